// Round 9
// baseline (167.219 us; speedup 1.0000x reference)
//
#include <hip/hip_runtime.h>

// LoopHead: node MLP (32->64->32) then edge decoder (gather/concat -> 64 -> 1)
// Counter-verified history: R10 TLP neutral; R12 VALU-shave neutral; R13 LDS
// pipeline regressed; R14 int8 FETCH 176->39MB but slower (+dequant VALU);
// R16 LDS scales, FETCH 27MB, still 86us (dequant VALU + 12-wave occupancy).
// Additive model fitting all rounds: dur ~ 22us base + 0.081us/VALU-inst +
// ~45us HBM-random term (only when z table > L2).
// R17: kill BOTH big terms at once -> int8 MFMA (mfma_i32_16x16x64_i8):
//   - gathered bytes ARE the B-frag (K=64 = zi||zj, 16B/lane, 2 instrs/iter,
//     64 sector touches = R12 shape) -> ZERO dequant VALU.
//   - per-node group-4 scales applied post-matmul: two masked MFMAs
//     (k<32 zi, k>=32 zj) share one A-frag (zeroed B half = A don't-care);
//     epilogue h = (si*acc1 + sj*acc2)*wsc_m + bias. Int accumulation exact.
//   - dw1 int8 per-output-row scale (rel err ~0.5%).
//   - no LDS, no syncthreads -> full occupancy; scales from 50KB L1-class
//     table (2 loads/iter).
// z8/scg generation = R16 verbatim (proven absmax 0.03125).
// R18 = byte-identical resubmit of R17 (infra failure, no data).

typedef short bfrag4 __attribute__((ext_vector_type(4)));  // 4 bf16 (x16 frag)
typedef float f32x4v __attribute__((ext_vector_type(4)));  // fp32 x4
typedef int   i32x4  __attribute__((ext_vector_type(4)));  // int32 x4 (16B)

#define N_NODES 100000
#define N_EDGES 3200000

__device__ __forceinline__ unsigned short f2bf(float f) {
    unsigned int i = __float_as_uint(f);
    unsigned int r = i + 0x7FFFu + ((i >> 16) & 1u);  // RNE
    return (unsigned short)(r >> 16);
}

__device__ __forceinline__ float bf2f(unsigned short b) {
    unsigned int u = ((unsigned int)b) << 16;
    return __uint_as_float(u);
}

__device__ __forceinline__ bfrag4 cvt4(float x0, float x1, float x2, float x3) {
    bfrag4 v;
    v[0] = (short)f2bf(x0);
    v[1] = (short)f2bf(x1);
    v[2] = (short)f2bf(x2);
    v[3] = (short)f2bf(x3);
    return v;
}

// ---------------- Kernel 1: node projection -> z8 + group-4 scales ---------
// (R16 verbatim — harness-proven, absmax 0.03125)
__global__ __launch_bounds__(256) void node_proj_kernel(
    const float* __restrict__ z_mod,   // [N,32] fp32
    const float* __restrict__ w1,      // [32,64] row-major (k,n)
    const float* __restrict__ b1,      // [64]
    const float* __restrict__ w2,      // [64,32] row-major (k,n)
    const float* __restrict__ b2,      // [32]
    char*           __restrict__ z8,      // [N,32] int8 out (workspace)
    unsigned short* __restrict__ scg)     // [N/4] bf16 group scales (ws)
{
    __shared__ unsigned short hbuf[4][16 * 72];

    const int tid  = threadIdx.x;
    const int wave = tid >> 6;
    const int lane = tid & 63;
    const int quad = lane >> 4;
    const int col  = lane & 15;

    bfrag4 bw1[2][4];   // stage 1: K=32 (2 steps), N=64 (4 n-tiles)
    float  bias1[4];
    for (int t = 0; t < 4; ++t) {
        const int n = col + 16 * t;
        for (int s = 0; s < 2; ++s)
            for (int j = 0; j < 4; ++j)
                bw1[s][t][j] = (short)f2bf(w1[(s * 16 + quad * 4 + j) * 64 + n]);
        bias1[t] = b1[n];
    }
    bfrag4 bw2[4][2];   // stage 2: K=64 (4 steps), N=32 (2 n-tiles)
    float  bias2[2];
    for (int t = 0; t < 2; ++t) {
        const int n = col + 16 * t;
        for (int s = 0; s < 4; ++s)
            for (int j = 0; j < 4; ++j)
                bw2[s][t][j] = (short)f2bf(w2[(s * 16 + quad * 4 + j) * 32 + n]);
        bias2[t] = b2[n];
    }

    unsigned short* hrow = &hbuf[wave][0];

    const int gwave  = blockIdx.x * 4 + wave;
    const int nwaves = gridDim.x * 4;
    const int ntiles = N_NODES / 16;   // 6250, exact

    for (int tile = gwave; tile < ntiles; tile += nwaves) {
        const int node0 = tile * 16;
        const float* zrow = z_mod + (size_t)(node0 + col) * 32;

        f32x4v za0 = *(const f32x4v*)(zrow + 0 * 16 + quad * 4);
        f32x4v za1 = *(const f32x4v*)(zrow + 1 * 16 + quad * 4);
        bfrag4 a10 = cvt4(za0[0], za0[1], za0[2], za0[3]);
        bfrag4 a11 = cvt4(za1[0], za1[1], za1[2], za1[3]);

        f32x4v acc[4];
        for (int t = 0; t < 4; ++t) {
            f32x4v c = {bias1[t], bias1[t], bias1[t], bias1[t]};
            c = __builtin_amdgcn_mfma_f32_16x16x16bf16_1k(a10, bw1[0][t], c, 0, 0, 0);
            c = __builtin_amdgcn_mfma_f32_16x16x16bf16_1k(a11, bw1[1][t], c, 0, 0, 0);
            acc[t] = c;
        }

        for (int t = 0; t < 4; ++t)
            for (int r = 0; r < 4; ++r) {
                float v = acc[t][r];
                v = v > 0.f ? v : 0.f;
                hrow[(quad * 4 + r) * 72 + (col + 16 * t)] = f2bf(v);
            }
        asm volatile("" ::: "memory");

        f32x4v acc2[2];
        for (int t = 0; t < 2; ++t)
            acc2[t] = (f32x4v){bias2[t], bias2[t], bias2[t], bias2[t]};
        for (int s = 0; s < 4; ++s) {
            bfrag4 a2 = *(const bfrag4*)(hrow + col * 72 + s * 16 + quad * 4);
            for (int t = 0; t < 2; ++t)
                acc2[t] = __builtin_amdgcn_mfma_f32_16x16x16bf16_1k(a2, bw2[s][t], acc2[t], 0, 0, 0);
        }
        asm volatile("" ::: "memory");

        // ---- int8 quantization epilogue: per-GROUP-of-4 scale -------------
        float am[4];
        for (int r = 0; r < 4; ++r)
            am[r] = fmaxf(fabsf(acc2[0][r]), fabsf(acc2[1][r]));
        for (int mask = 1; mask <= 8; mask <<= 1)
            for (int r = 0; r < 4; ++r)
                am[r] = fmaxf(am[r], __shfl_xor(am[r], mask, 64));
        const float gm = fmaxf(fmaxf(am[0], am[1]), fmaxf(am[2], am[3]));
        const float inv = 127.f / fmaxf(gm, 1e-30f);

        char* hb = (char*)hrow;   // reuse hbuf as [16][32] byte buffer
        for (int r = 0; r < 4; ++r)
            for (int t = 0; t < 2; ++t) {
                int q = (int)rintf(acc2[t][r] * inv);
                hb[(quad * 4 + r) * 32 + (col + 16 * t)] = (char)q;
            }
        if (col == 0)
            scg[(node0 >> 2) + quad] = f2bf(gm * (1.f / 127.f));
        asm volatile("" ::: "memory");

        *(unsigned long long*)(z8 + (size_t)node0 * 32 + lane * 8) =
            *(const unsigned long long*)(hb + lane * 8);
        asm volatile("" ::: "memory");
    }
}

// ---------------- Kernel 2: edge decoder (R17: i8 MFMA, no dequant) --------
__global__ __launch_bounds__(256) void edge_dec_kernel(
    const int*            __restrict__ eidx,   // [2, E] int32
    const char*           __restrict__ z8,     // [N,32] int8
    const unsigned short* __restrict__ scg,    // [N/4] bf16 group scales
    const float*          __restrict__ dw1,    // [64,64] row-major (k,n)
    const float*          __restrict__ db1,    // [64]
    const float*          __restrict__ dw2,    // [64]
    const float*          __restrict__ db2,    // [1]
    float* __restrict__ out)                   // [E] fp32
{
    const int tid  = threadIdx.x;
    const int lane = tid & 63;
    const int quad = lane >> 4;
    const int col  = lane & 15;
    const int ss   = quad >> 1;   // 0 = src row (zi), 1 = dst row (zj)
    const int hf   = quad & 1;    // which 16B half of the 32B int8 row

    // ---- preamble: int8-quantize dw1^T per output row m -------------------
    // A-frag (i8 16x16x64): lane(col,quad) holds A[m=16mt+col][k=quad*16+j],
    // j=0..15 -> 16 bytes = 4 regs. One frag serves both masked calls.
    i32x4  awq[4];
    float  wscv[4];      // weight scale at m = 16mt+col (A-layout)
    for (int mt = 0; mt < 4; ++mt) {
        const int m = 16 * mt + col;
        float w[16];
        float mx = 0.f;
        for (int j = 0; j < 16; ++j) {
            w[j] = dw1[(quad * 16 + j) * 64 + m];
            mx = fmaxf(mx, fabsf(w[j]));
        }
        mx = fmaxf(mx, __shfl_xor(mx, 16, 64));
        mx = fmaxf(mx, __shfl_xor(mx, 32, 64));
        wscv[mt] = mx * (1.f / 127.f);
        const float winv = 127.f / fmaxf(mx, 1e-30f);
        i32x4 a;
        for (int rr = 0; rr < 4; ++rr) {
            int pk = 0;
            for (int bi = 0; bi < 4; ++bi) {
                int q = (int)rintf(w[rr * 4 + bi] * winv);
                pk |= (q & 0xFF) << (8 * bi);
            }
            a[rr] = pk;
        }
        awq[mt] = a;
    }
    // epilogue-layout constants: index by m = 16mt + quad*4 + r (C-layout)
    float wsce[4][4], bias1v[4][4], w2v[4][4];
    for (int mt = 0; mt < 4; ++mt)
        for (int r = 0; r < 4; ++r) {
            wsce[mt][r]   = __shfl(wscv[mt], quad * 4 + r, 64);
            bias1v[mt][r] = db1[16 * mt + quad * 4 + r];
            w2v[mt][r]    = dw2[16 * mt + quad * 4 + r];
        }
    const float bias2 = db2[0];
    const int mlo = (quad < 2) ? -1 : 0;   // B-mask: keep k<32 (zi) lanes
    const int mhi = ~mlo;                  // keep k>=32 (zj) lanes

    const int gwave  = blockIdx.x * 4 + (tid >> 6);
    const int nwaves = gridDim.x * 4;     // 8192
    const int npairs = N_EDGES / 32;      // 100000, exact

    const int iofs = ss * N_EDGES + col;  // this lane's index column

    // prefetch first iteration's node indices (tile A: edges e0+col,
    // tile B: e0+16+col; lane reads src or dst index per ss)
    int iA = eidx[gwave * 32 + iofs];
    int iB = eidx[gwave * 32 + 16 + iofs];

    for (int p = gwave; p < npairs; p += nwaves) {
        const int e0 = p * 32;

        // 2 row-gathers (16B/lane; 2 lanes per 32B row -> 64B-sector pairs)
        // + 2 scale loads from the 50KB L1-class table. The gathered bytes
        // ARE the i8 B-fragment: k = quad*16+j = (zi||zj)[.] by construction.
        i32x4 gA = *(const i32x4*)(z8 + (size_t)iA * 32 + hf * 16);
        i32x4 gB = *(const i32x4*)(z8 + (size_t)iB * 32 + hf * 16);
        float scA = bf2f(scg[iA >> 2]);
        float scB = bf2f(scg[iB >> 2]);

        // prefetch NEXT iteration's indices (branchless clamp — always valid)
        const int pn = p + nwaves;
        const int pc = pn < npairs ? pn : gwave;
        iA = eidx[pc * 32 + iofs];
        iB = eidx[pc * 32 + 16 + iofs];

        const i32x4 zc = {0, 0, 0, 0};

        // ---- tile A: edges e0..e0+15 ----
        i32x4 b1, b2;
        for (int i = 0; i < 4; ++i) { b1[i] = gA[i] & mlo; b2[i] = gA[i] & mhi; }
        i32x4 a1[4], a2[4];
        for (int mt = 0; mt < 4; ++mt) {
            a1[mt] = __builtin_amdgcn_mfma_i32_16x16x64_i8(awq[mt], b1, zc, 0, 0, 0);
            a2[mt] = __builtin_amdgcn_mfma_i32_16x16x64_i8(awq[mt], b2, zc, 0, 0, 0);
        }
        float si = __shfl(scA, col, 64);        // src scale of edge col
        float sj = __shfl(scA, 32 + col, 64);   // dst scale of edge col
        float pA = 0.f;
        for (int mt = 0; mt < 4; ++mt)
            for (int r = 0; r < 4; ++r) {
                float t = (float)a1[mt][r] * si;
                t = fmaf((float)a2[mt][r], sj, t);
                float h = fmaf(t, wsce[mt][r], bias1v[mt][r]);
                h = h > 0.f ? h : 0.f;
                pA = fmaf(h, w2v[mt][r], pA);
            }
        pA += __shfl_xor(pA, 16, 64);
        pA += __shfl_xor(pA, 32, 64);

        // ---- tile B: edges e0+16..e0+31 ----
        for (int i = 0; i < 4; ++i) { b1[i] = gB[i] & mlo; b2[i] = gB[i] & mhi; }
        for (int mt = 0; mt < 4; ++mt) {
            a1[mt] = __builtin_amdgcn_mfma_i32_16x16x64_i8(awq[mt], b1, zc, 0, 0, 0);
            a2[mt] = __builtin_amdgcn_mfma_i32_16x16x64_i8(awq[mt], b2, zc, 0, 0, 0);
        }
        si = __shfl(scB, col, 64);
        sj = __shfl(scB, 32 + col, 64);
        float pB = 0.f;
        for (int mt = 0; mt < 4; ++mt)
            for (int r = 0; r < 4; ++r) {
                float t = (float)a1[mt][r] * si;
                t = fmaf((float)a2[mt][r], sj, t);
                float h = fmaf(t, wsce[mt][r], bias1v[mt][r]);
                h = h > 0.f ? h : 0.f;
                pB = fmaf(h, w2v[mt][r], pB);
            }
        pB += __shfl_xor(pB, 16, 64);
        pB += __shfl_xor(pB, 32, 64);

        // lanes 0-15: edge e0+lane (tile A); 16-31: e0+lane (tile B).
        if (lane < 32) {
            float v = (lane < 16 ? pA : pB) + bias2;
            out[e0 + lane] = v;
        }
    }
}

extern "C" void kernel_launch(void* const* d_in, const int* in_sizes, int n_in,
                              void* d_out, int out_size, void* d_ws, size_t ws_size,
                              hipStream_t stream) {
    const float* z_mod = (const float*)d_in[0];
    const int*   eidx  = (const int*)d_in[1];
    const float* w1    = (const float*)d_in[2];
    const float* b1    = (const float*)d_in[3];
    const float* w2    = (const float*)d_in[4];
    const float* b2    = (const float*)d_in[5];
    const float* dw1   = (const float*)d_in[6];
    const float* db1   = (const float*)d_in[7];
    const float* dw2   = (const float*)d_in[8];
    const float* db2   = (const float*)d_in[9];
    float* out = (float*)d_out;

    char*           z8  = (char*)d_ws;                                // 3.2 MB
    unsigned short* scg = (unsigned short*)((char*)d_ws + (size_t)N_NODES * 32);

    node_proj_kernel<<<512, 256, 0, stream>>>(z_mod, w1, b1, w2, b2, z8, scg);
    // no LDS, no syncthreads -> occupancy bound only by VGPR
    edge_dec_kernel<<<2048, 256, 0, stream>>>(eidx, z8, scg, dw1, db1, dw2, db2, out);
}